// Round 6
// baseline (1075.166 us; speedup 1.0000x reference)
//
#include <hip/hip_runtime.h>
#include <hip/hip_fp16.h>

// RandDCGRUCell on MI355X.
// B=64, N=2000, IN_DIM=2, U=64, D=66, NSUP=2, K=2, M=5.
// R5 pass: 1019 us, absmax 0.0518. k_proj = 2x252 us, VALU-bound (72% busy,
// 0 MFMA, 6% HBM), 4.2e7 LDS bank conflicts.
// R6: k_proj rewritten around v_dot2_f32_f16 (fp16 pair inputs, fp32
// accumulate -> same numerics class as before): halves MAC instructions,
// removes all cvt_f32_f16, W pre-packed fp16-transposed [o][180] with
// K-order k' = m*66+d (m-major) so dot2 pairs are adjacent in X storage.
// Single-stage 46.3KB LDS, row stride 181 dwords => 2-way-only bank aliasing.
// SpMM chain untouched.

#define N_NODES 2000
#define BATCH   64
#define DFEAT   66
#define DPAD    72           // X row pad: 36 half2 per m, d>=66 zeroed
#define WROW    (BATCH*DPAD) // 4608 halfs per (n, matrix)
#define MMATS   5
#define ELLW    128
#define KP2     180          // packed dpairs: 5 m * 36 (dpl>=33 zero)
#define RS      181          // LDS row stride in dwords (bank-safe)

typedef __half h16;

typedef _Float16 f16x2 __attribute__((ext_vector_type(2)));

__device__ __forceinline__ __half2 f2h2(float a, float b) {
  __half2 r; r.x = __float2half_rn(a); r.y = __float2half_rn(b); return r;
}
__device__ __forceinline__ unsigned int packh(float a, float b) {
  __half2 h = f2h2(a, b);
  return __builtin_bit_cast(unsigned int, h);
}
__device__ __forceinline__ float dot2f(unsigned int a, unsigned int b, float c) {
#if __has_builtin(__builtin_amdgcn_fdot2)
  return __builtin_amdgcn_fdot2(__builtin_bit_cast(f16x2, a),
                                __builtin_bit_cast(f16x2, b), c, false);
#else
  __half2 ah = __builtin_bit_cast(__half2, a);
  __half2 bh = __builtin_bit_cast(__half2, b);
  float2 af = __half22float2(ah), bf = __half22float2(bh);
  return fmaf(af.y, bf.y, fmaf(af.x, bf.x, c));
#endif
}

// ---------------- weights: build fp16-transposed packed Wt ----------
// Wt[o][k'] half2 = (w(d=2dpl,m), w(d=2dpl+1,m)), k' = m*36+dpl, dpl>=33 -> 0
// w = mu + exp(log_sig)*eps ; original W row index = d*5 + m.
__global__ __launch_bounds__(256) void k_weights(
    const float* __restrict__ mu_w_ru, const float* __restrict__ ls_w_ru, const float* __restrict__ eps_w_ru,
    const float* __restrict__ mu_b_ru, const float* __restrict__ ls_b_ru, const float* __restrict__ eps_b_ru,
    const float* __restrict__ mu_w_c,  const float* __restrict__ ls_w_c,  const float* __restrict__ eps_w_c,
    const float* __restrict__ mu_b_c,  const float* __restrict__ ls_b_c,  const float* __restrict__ eps_b_c,
    unsigned int* __restrict__ Wtru, float* __restrict__ bru,
    unsigned int* __restrict__ Wtc,  float* __restrict__ bc)
{
  int idx = blockIdx.x*256 + threadIdx.x;
  const int n_ru = 128*KP2, n_c = 64*KP2;   // 23040, 11520
  if (idx < n_ru) {
    int o = idx / KP2, c = idx - o*KP2;
    int m = c / 36, dpl = c - m*36;
    unsigned int r = 0;
    if (dpl < 33) {
      int r0 = ((2*dpl)*MMATS + m)*128 + o;
      int r1 = ((2*dpl+1)*MMATS + m)*128 + o;
      float w0 = mu_w_ru[r0] + expf(ls_w_ru[r0]) * eps_w_ru[r0];
      float w1 = mu_w_ru[r1] + expf(ls_w_ru[r1]) * eps_w_ru[r1];
      r = packh(w0, w1);
    }
    Wtru[idx] = r;
  } else if (idx < n_ru + n_c) {
    int i = idx - n_ru;
    int o = i / KP2, c = i - o*KP2;
    int m = c / 36, dpl = c - m*36;
    unsigned int r = 0;
    if (dpl < 33) {
      int r0 = ((2*dpl)*MMATS + m)*64 + o;
      int r1 = ((2*dpl+1)*MMATS + m)*64 + o;
      float w0 = mu_w_c[r0] + expf(ls_w_c[r0]) * eps_w_c[r0];
      float w1 = mu_w_c[r1] + expf(ls_w_c[r1]) * eps_w_c[r1];
      r = packh(w0, w1);
    }
    Wtc[i] = r;
  } else if (idx < n_ru + n_c + 128) {
    int i = idx - n_ru - n_c;
    bru[i] = mu_b_ru[i] + expf(ls_b_ru[i]) * eps_b_ru[i];
  } else if (idx < n_ru + n_c + 128 + 64) {
    int i = idx - n_ru - n_c - 128;
    bc[i] = mu_b_c[i] + expf(ls_b_c[i]) * eps_b_c[i];
  }
}

// ---------------- ELL build (order within row irrelevant for a sum) --
__global__ __launch_bounds__(256) void k_ell(
    const float* __restrict__ supp, unsigned short* __restrict__ cols,
    float* __restrict__ vals, int* __restrict__ cnt)
{
  int j = blockIdx.x*256 + threadIdx.x;
  if (j >= N_NODES) return;
  int n = blockIdx.y, s = blockIdx.z;
  int r = s*N_NODES + n;
  float v = supp[(size_t)r*N_NODES + j];
  if (v != 0.f) {
    int p = atomicAdd(cnt + r, 1);
    if (p < ELLW) {
      cols[(size_t)r*ELLW + p] = (unsigned short)j;
      vals[(size_t)r*ELLW + p] = v;
    }
  }
}

// ---------------- build x0 [n][b][DPAD] fp16 ------------------------
__global__ __launch_bounds__(256) void k_build0(
    const float* __restrict__ inp, const float* __restrict__ hx,
    const h16* __restrict__ VALr, h16* __restrict__ xb, int mode)
{
  int n = blockIdx.x;
  for (int idx = threadIdx.x; idx < WROW; idx += 256) {
    int b = idx / DPAD, d = idx % DPAD;
    float v = 0.f;
    if (d < 2) {
      v = inp[(size_t)b*(N_NODES*2) + n*2 + d];
    } else if (d < DFEAT) {
      float hv = hx[(size_t)b*(N_NODES*64) + n*64 + (d-2)];
      if (mode == 1) hv *= __half2float(VALr[((size_t)b*N_NODES + n)*128 + (d-2)]); // r gate
      v = hv;
    }
    xb[(size_t)n*WROW + idx] = __float2half_rn(v);
  }
}

// ---------------- SpMM: x1 = S @ x0 (both supports, fp16) ------------
__global__ __launch_bounds__(256) void k_spmm(
    h16* __restrict__ dst0, h16* __restrict__ dst1,
    const h16* __restrict__ src, const unsigned short* __restrict__ cols,
    const float* __restrict__ vals, const int* __restrict__ cnt)
{
  const int n = blockIdx.x, s = blockIdx.y, t = threadIdx.x;
  const int r = s*N_NODES + n;
  int c = cnt[r]; if (c > ELLW) c = ELLW;
  const unsigned short* cp = cols + (size_t)r*ELLW;
  const float*          vp = vals + (size_t)r*ELLW;
  float2 acc[9];
  #pragma unroll
  for (int i = 0; i < 9; ++i) acc[i] = make_float2(0.f, 0.f);
  const __half2* sb = (const __half2*)src;
  for (int k = 0; k < c; ++k) {
    int j = cp[k]; float v = vp[k];
    const __half2* s0 = sb + (size_t)j*(WROW/2) + t;
    #pragma unroll
    for (int i = 0; i < 9; ++i) {
      float2 f = __half22float2(s0[i*256]);
      acc[i].x = fmaf(v, f.x, acc[i].x);
      acc[i].y = fmaf(v, f.y, acc[i].y);
    }
  }
  __half2* dp = (__half2*)(s ? dst1 : dst0) + (size_t)n*(WROW/2) + t;
  #pragma unroll
  for (int i = 0; i < 9; ++i) dp[i*256] = f2h2(acc[i].x, acc[i].y);
}

// ---------------- Chebyshev: x2 = 2*(S @ x1) - x0 (both supports) ----
__global__ __launch_bounds__(256) void k_cheb(
    h16* __restrict__ dst0, h16* __restrict__ dst1,
    const h16* __restrict__ src0, const h16* __restrict__ src1,
    const h16* __restrict__ x0, const unsigned short* __restrict__ cols,
    const float* __restrict__ vals, const int* __restrict__ cnt)
{
  const int n = blockIdx.x, s = blockIdx.y, t = threadIdx.x;
  const int r = s*N_NODES + n;
  int c = cnt[r]; if (c > ELLW) c = ELLW;
  const unsigned short* cp = cols + (size_t)r*ELLW;
  const float*          vp = vals + (size_t)r*ELLW;
  float2 acc[9];
  #pragma unroll
  for (int i = 0; i < 9; ++i) acc[i] = make_float2(0.f, 0.f);
  const __half2* sb = (const __half2*)(s ? src1 : src0);
  for (int k = 0; k < c; ++k) {
    int j = cp[k]; float v = vp[k];
    const __half2* s0 = sb + (size_t)j*(WROW/2) + t;
    #pragma unroll
    for (int i = 0; i < 9; ++i) {
      float2 f = __half22float2(s0[i*256]);
      acc[i].x = fmaf(v, f.x, acc[i].x);
      acc[i].y = fmaf(v, f.y, acc[i].y);
    }
  }
  const __half2* xp = (const __half2*)x0 + (size_t)n*(WROW/2) + t;
  __half2* dp = (__half2*)(s ? dst1 : dst0) + (size_t)n*(WROW/2) + t;
  #pragma unroll
  for (int i = 0; i < 9; ++i) {
    float2 f = __half22float2(xp[i*256]);
    dp[i*256] = f2h2(2.f*acc[i].x - f.x, 2.f*acc[i].y - f.y);
  }
}

// ---------------- projection via v_dot2_f32_f16 ----------------------
// Per (n, hh): [64b x 360k'] @ [360k' x 64o], k' = m*72+d (m-major, padded).
// X pairs (d,d+1) are adjacent half2 in X storage; Wt rows pre-permuted.
// mode 0: VAL[b][n][o0..] = sigmoid(acc+bias) fp16   (hh=0,1)
// mode 1: out = u*hx + (1-u)*tanh(acc+bias)  fp32    (hh=0)
__global__ __launch_bounds__(256) void k_proj(
    const h16* __restrict__ Xh, const unsigned int* __restrict__ Wt,
    const float* __restrict__ bias, h16* __restrict__ VAL,
    const float* __restrict__ hx, const h16* __restrict__ VALu,
    float* __restrict__ out, int mode)
{
  __shared__ unsigned int Wl[64*RS];       // 46,336 B
  const int n = blockIdx.x, hh = blockIdx.y;
  const int t = threadIdx.x;
  for (int i = t; i < 64*KP2; i += 256) {
    int o = i / KP2, c = i - o*KP2;
    Wl[o*RS + c] = Wt[(size_t)(hh*64 + o)*KP2 + c];
  }
  __syncthreads();

  const int og = t & 15, bg = t >> 4;      // 16 o-groups x 16 b-groups
  float acc[4][4];
  #pragma unroll
  for (int j = 0; j < 4; ++j)
    #pragma unroll
    for (int i = 0; i < 4; ++i) acc[j][i] = 0.f;

  const size_t NSF2 = (size_t)N_NODES * (WROW/2);       // uints per matrix
  const unsigned int* xn = (const unsigned int*)Xh + (size_t)n*(WROW/2);

  #pragma unroll
  for (int m = 0; m < MMATS; ++m) {
    const unsigned int* xm = xn + (size_t)m*NSF2;       // [b][36] half2
    const unsigned int* wm = Wl + m*36;
    for (int dp = 0; dp < 36; dp += 4) {
      uint4 xv[4];
      #pragma unroll
      for (int j = 0; j < 4; ++j)
        xv[j] = *(const uint4*)(xm + (size_t)(bg*4 + j)*36 + dp);
      #pragma unroll
      for (int q = 0; q < 4; ++q) {
        #pragma unroll
        for (int oi = 0; oi < 4; ++oi) {
          unsigned int wv = wm[(og*4 + oi)*RS + dp + q];
          #pragma unroll
          for (int j = 0; j < 4; ++j)
            acc[j][oi] = dot2f(reinterpret_cast<const unsigned int*>(&xv[j])[q], wv, acc[j][oi]);
        }
      }
    }
  }

  const int o0 = hh*64 + og*4;
  if (mode == 0) {
    #pragma unroll
    for (int j = 0; j < 4; ++j) {
      int b = bg*4 + j;
      size_t base = ((size_t)b*N_NODES + n)*128 + o0;   // o0 % 4 == 0
      float s0 = 1.f/(1.f + expf(-(acc[j][0] + bias[o0+0])));
      float s1 = 1.f/(1.f + expf(-(acc[j][1] + bias[o0+1])));
      float s2 = 1.f/(1.f + expf(-(acc[j][2] + bias[o0+2])));
      float s3 = 1.f/(1.f + expf(-(acc[j][3] + bias[o0+3])));
      __half2* vp = (__half2*)(VAL + base);
      vp[0] = f2h2(s0, s1);
      vp[1] = f2h2(s2, s3);
    }
  } else {
    #pragma unroll
    for (int j = 0; j < 4; ++j) {
      int b = bg*4 + j;
      size_t vbase = ((size_t)b*N_NODES + n)*128 + 64 + o0;
      size_t obase = (size_t)b*(N_NODES*64) + n*64 + o0;  // 4-elem aligned
      float r0[4];
      #pragma unroll
      for (int i = 0; i < 4; ++i) {
        float cc = tanhf(acc[j][i] + bias[o0 + i]);
        float u  = __half2float(VALu[vbase + i]);
        float h  = hx[obase + i];
        r0[i] = u*h + (1.f - u)*cc;
      }
      *reinterpret_cast<float4*>(out + obase) = make_float4(r0[0], r0[1], r0[2], r0[3]);
    }
  }
}

extern "C" void kernel_launch(void* const* d_in, const int* in_sizes, int n_in,
                              void* d_out, int out_size, void* d_ws, size_t ws_size,
                              hipStream_t stream)
{
  const float* inp      = (const float*)d_in[0];
  const float* hx       = (const float*)d_in[1];
  const float* supp     = (const float*)d_in[2];
  const float* mu_w_ru  = (const float*)d_in[3];
  const float* ls_w_ru  = (const float*)d_in[4];
  const float* mu_b_ru  = (const float*)d_in[5];
  const float* ls_b_ru  = (const float*)d_in[6];
  const float* eps_w_ru = (const float*)d_in[7];
  const float* eps_b_ru = (const float*)d_in[8];
  const float* mu_w_c   = (const float*)d_in[9];
  const float* ls_w_c   = (const float*)d_in[10];
  const float* mu_b_c   = (const float*)d_in[11];
  const float* ls_b_c   = (const float*)d_in[12];
  const float* eps_w_c  = (const float*)d_in[13];
  const float* eps_b_c  = (const float*)d_in[14];
  float* out = (float*)d_out;

  char* wsp = (char*)d_ws;
  size_t off = 0;
  auto take = [&](size_t bytes) -> void* {
    void* p = wsp + off;
    off = (off + bytes + 255) & ~(size_t)255;
    return p;
  };
  const size_t NSF = (size_t)N_NODES * WROW;                 // 9,216,000
  h16*   Xh  = (h16*)  take(5*NSF*sizeof(h16));              //  92.2 MB
  h16*   VAL = (h16*)  take((size_t)BATCH*N_NODES*128*sizeof(h16)); // 32.8 MB
  unsigned int* Wtru = (unsigned int*)take((size_t)128*KP2*sizeof(unsigned int));
  unsigned int* Wtc  = (unsigned int*)take((size_t)64*KP2*sizeof(unsigned int));
  float* bru = (float*)take(128*sizeof(float));
  float* bc  = (float*)take(64*sizeof(float));
  unsigned short* ellc = (unsigned short*)take((size_t)2*N_NODES*ELLW*sizeof(unsigned short));
  float* ellv= (float*)take((size_t)2*N_NODES*ELLW*sizeof(float));
  int*   cnt = (int*)  take((size_t)2*N_NODES*sizeof(int));
  // total ~128.5 MB (R5 ran at this footprint)
  (void)ws_size;

  hipMemsetAsync(cnt, 0, (size_t)2*N_NODES*sizeof(int), stream);
  k_weights<<<136, 256, 0, stream>>>(mu_w_ru, ls_w_ru, eps_w_ru,
                                     mu_b_ru, ls_b_ru, eps_b_ru,
                                     mu_w_c, ls_w_c, eps_w_c,
                                     mu_b_c, ls_b_c, eps_b_c,
                                     Wtru, bru, Wtc, bc);
  k_ell<<<dim3(8, N_NODES, 2), 256, 0, stream>>>(supp, ellc, ellv, cnt);

  h16* X0 = Xh;
  h16* X1 = Xh +   NSF;
  h16* X2 = Xh + 2*NSF;
  h16* X3 = Xh + 3*NSF;
  h16* X4 = Xh + 4*NSF;

  for (int pass = 0; pass < 2; ++pass) {
    k_build0<<<N_NODES, 256, 0, stream>>>(inp, hx, VAL, X0, pass);
    k_spmm <<<dim3(N_NODES, 2), 256, 0, stream>>>(X1, X3, X0, ellc, ellv, cnt);
    k_cheb <<<dim3(N_NODES, 2), 256, 0, stream>>>(X2, X4, X1, X3, X0, ellc, ellv, cnt);
    if (pass == 0)
      k_proj<<<dim3(N_NODES, 2), 256, 0, stream>>>(Xh, Wtru, bru, VAL,
                                                   nullptr, nullptr, nullptr, 0);
    else
      k_proj<<<dim3(N_NODES, 1), 256, 0, stream>>>(Xh, Wtc, bc, nullptr,
                                                   hx, VAL, out, 1);
  }
}

// Round 7
// 881.656 us; speedup vs baseline: 1.2195x; 1.2195x over previous
//
#include <hip/hip_runtime.h>
#include <hip/hip_fp16.h>

// RandDCGRUCell on MI355X.
// B=64, N=2000, IN_DIM=2, U=64, D=66, NSUP=2, K=2, M=5.
// R6 post-mortem: dot2 k_proj regressed (VGPR 40->196, occupancy 32->11%,
// unroll-driven). R7: projection via MFMA v_mfma_f32_16x16x32_f16.
//  - X staged in LDS k-packed (k=m*66+d, pad->352), row stride 360 halves
//    (lane stride 20 mod 32 banks -> 2-way only, free).
//  - W pre-swizzled in k_weights to per-lane fragment order -> coalesced
//    16B b-frag loads, L2-resident.
//  - Layouts (guide-verified): A[m=lane&15][k=quad*8+j],
//    B[k=quad*8+j][n=lane&15], D[row=quad*4+r][col=lane&15].
// SpMM chain untouched.

#define N_NODES 2000
#define BATCH   64
#define DFEAT   66
#define DPAD    72           // X plane row pad (halfs)
#define WROW    (BATCH*DPAD) // 4608 halfs per (n, matrix)
#define MMATS   5
#define ELLW    128
#define KPK     352          // packed K (330 padded to 11*32)
#define XLS     360          // LDS row stride in halfs (180 dwords, bank-safe)

typedef __half h16;
typedef _Float16 f16x8 __attribute__((ext_vector_type(8)));
typedef float    f32x4 __attribute__((ext_vector_type(4)));

__device__ __forceinline__ __half2 f2h2(float a, float b) {
  __half2 r; r.x = __float2half_rn(a); r.y = __float2half_rn(b); return r;
}

// ---------------- weights: fragment-order swizzled fp16 W -----------
// Wz[((ot*11 + k0)*64 + lane)*8 + j] = W[k][o],  k = k0*32 + (lane>>4)*8 + j,
// o = ot*16 + (lane&15), k-order k = m*66+d, original row = d*5+m, k>=330 -> 0.
__global__ __launch_bounds__(256) void k_weights(
    const float* __restrict__ mu_w_ru, const float* __restrict__ ls_w_ru, const float* __restrict__ eps_w_ru,
    const float* __restrict__ mu_b_ru, const float* __restrict__ ls_b_ru, const float* __restrict__ eps_b_ru,
    const float* __restrict__ mu_w_c,  const float* __restrict__ ls_w_c,  const float* __restrict__ eps_w_c,
    const float* __restrict__ mu_b_c,  const float* __restrict__ ls_b_c,  const float* __restrict__ eps_b_c,
    h16* __restrict__ Wzru, float* __restrict__ bru,
    h16* __restrict__ Wzc,  float* __restrict__ bc)
{
  int idx = blockIdx.x*256 + threadIdx.x;
  const int n_ru = 8*11*64*8;   // 45056
  const int n_c  = 4*11*64*8;   // 22528
  if (idx < n_ru) {
    int j = idx & 7, ln = (idx >> 3) & 63, rest = idx >> 9;
    int k = (rest % 11)*32 + (ln >> 4)*8 + j;
    int o = (rest / 11)*16 + (ln & 15);
    float wv = 0.f;
    if (k < 330) {
      int m = k/66, d = k - m*66;
      int r = (d*MMATS + m)*128 + o;
      wv = mu_w_ru[r] + expf(ls_w_ru[r]) * eps_w_ru[r];
    }
    Wzru[idx] = __float2half_rn(wv);
  } else if (idx < n_ru + n_c) {
    int i = idx - n_ru;
    int j = i & 7, ln = (i >> 3) & 63, rest = i >> 9;
    int k = (rest % 11)*32 + (ln >> 4)*8 + j;
    int o = (rest / 11)*16 + (ln & 15);
    float wv = 0.f;
    if (k < 330) {
      int m = k/66, d = k - m*66;
      int r = (d*MMATS + m)*64 + o;
      wv = mu_w_c[r] + expf(ls_w_c[r]) * eps_w_c[r];
    }
    Wzc[i] = __float2half_rn(wv);
  } else if (idx < n_ru + n_c + 128) {
    int i = idx - n_ru - n_c;
    bru[i] = mu_b_ru[i] + expf(ls_b_ru[i]) * eps_b_ru[i];
  } else if (idx < n_ru + n_c + 128 + 64) {
    int i = idx - n_ru - n_c - 128;
    bc[i] = mu_b_c[i] + expf(ls_b_c[i]) * eps_b_c[i];
  }
}

// ---------------- ELL build (order within row irrelevant for a sum) --
__global__ __launch_bounds__(256) void k_ell(
    const float* __restrict__ supp, unsigned short* __restrict__ cols,
    float* __restrict__ vals, int* __restrict__ cnt)
{
  int j = blockIdx.x*256 + threadIdx.x;
  if (j >= N_NODES) return;
  int n = blockIdx.y, s = blockIdx.z;
  int r = s*N_NODES + n;
  float v = supp[(size_t)r*N_NODES + j];
  if (v != 0.f) {
    int p = atomicAdd(cnt + r, 1);
    if (p < ELLW) {
      cols[(size_t)r*ELLW + p] = (unsigned short)j;
      vals[(size_t)r*ELLW + p] = v;
    }
  }
}

// ---------------- build x0 [n][b][DPAD] fp16 ------------------------
__global__ __launch_bounds__(256) void k_build0(
    const float* __restrict__ inp, const float* __restrict__ hx,
    const h16* __restrict__ VALr, h16* __restrict__ xb, int mode)
{
  int n = blockIdx.x;
  for (int idx = threadIdx.x; idx < WROW; idx += 256) {
    int b = idx / DPAD, d = idx % DPAD;
    float v = 0.f;
    if (d < 2) {
      v = inp[(size_t)b*(N_NODES*2) + n*2 + d];
    } else if (d < DFEAT) {
      float hv = hx[(size_t)b*(N_NODES*64) + n*64 + (d-2)];
      if (mode == 1) hv *= __half2float(VALr[((size_t)b*N_NODES + n)*128 + (d-2)]); // r gate
      v = hv;
    }
    xb[(size_t)n*WROW + idx] = __float2half_rn(v);
  }
}

// ---------------- SpMM: x1 = S @ x0 (both supports, fp16) ------------
__global__ __launch_bounds__(256) void k_spmm(
    h16* __restrict__ dst0, h16* __restrict__ dst1,
    const h16* __restrict__ src, const unsigned short* __restrict__ cols,
    const float* __restrict__ vals, const int* __restrict__ cnt)
{
  const int n = blockIdx.x, s = blockIdx.y, t = threadIdx.x;
  const int r = s*N_NODES + n;
  int c = cnt[r]; if (c > ELLW) c = ELLW;
  const unsigned short* cp = cols + (size_t)r*ELLW;
  const float*          vp = vals + (size_t)r*ELLW;
  float2 acc[9];
  #pragma unroll
  for (int i = 0; i < 9; ++i) acc[i] = make_float2(0.f, 0.f);
  const __half2* sb = (const __half2*)src;
  for (int k = 0; k < c; ++k) {
    int j = cp[k]; float v = vp[k];
    const __half2* s0 = sb + (size_t)j*(WROW/2) + t;
    #pragma unroll
    for (int i = 0; i < 9; ++i) {
      float2 f = __half22float2(s0[i*256]);
      acc[i].x = fmaf(v, f.x, acc[i].x);
      acc[i].y = fmaf(v, f.y, acc[i].y);
    }
  }
  __half2* dp = (__half2*)(s ? dst1 : dst0) + (size_t)n*(WROW/2) + t;
  #pragma unroll
  for (int i = 0; i < 9; ++i) dp[i*256] = f2h2(acc[i].x, acc[i].y);
}

// ---------------- Chebyshev: x2 = 2*(S @ x1) - x0 (both supports) ----
__global__ __launch_bounds__(256) void k_cheb(
    h16* __restrict__ dst0, h16* __restrict__ dst1,
    const h16* __restrict__ src0, const h16* __restrict__ src1,
    const h16* __restrict__ x0, const unsigned short* __restrict__ cols,
    const float* __restrict__ vals, const int* __restrict__ cnt)
{
  const int n = blockIdx.x, s = blockIdx.y, t = threadIdx.x;
  const int r = s*N_NODES + n;
  int c = cnt[r]; if (c > ELLW) c = ELLW;
  const unsigned short* cp = cols + (size_t)r*ELLW;
  const float*          vp = vals + (size_t)r*ELLW;
  float2 acc[9];
  #pragma unroll
  for (int i = 0; i < 9; ++i) acc[i] = make_float2(0.f, 0.f);
  const __half2* sb = (const __half2*)(s ? src1 : src0);
  for (int k = 0; k < c; ++k) {
    int j = cp[k]; float v = vp[k];
    const __half2* s0 = sb + (size_t)j*(WROW/2) + t;
    #pragma unroll
    for (int i = 0; i < 9; ++i) {
      float2 f = __half22float2(s0[i*256]);
      acc[i].x = fmaf(v, f.x, acc[i].x);
      acc[i].y = fmaf(v, f.y, acc[i].y);
    }
  }
  const __half2* xp = (const __half2*)x0 + (size_t)n*(WROW/2) + t;
  __half2* dp = (__half2*)(s ? dst1 : dst0) + (size_t)n*(WROW/2) + t;
  #pragma unroll
  for (int i = 0; i < 9; ++i) {
    float2 f = __half22float2(xp[i*256]);
    dp[i*256] = f2h2(2.f*acc[i].x - f.x, 2.f*acc[i].y - f.y);
  }
}

// ---------------- projection via MFMA 16x16x32 f16 -------------------
// Per block: node n, C[64b x (nt*16)o] = XL[64 x 352] * Wz[352 x nt*16].
// Wave w owns b-rows [16w,16w+16); 11 K-steps; nt o-tiles.
// mode 0: VAL[b][n][o] = sigmoid(acc+bias) fp16  (nt=8, o in [0,128))
// mode 1: out = u*hx + (1-u)*tanh(acc+bias) fp32 (nt=4, o in [0,64))
__global__ __launch_bounds__(256) void k_projm(
    const h16* __restrict__ Xh, const h16* __restrict__ Wz,
    const float* __restrict__ bias, h16* __restrict__ VAL,
    const float* __restrict__ hx, const h16* __restrict__ VALu,
    float* __restrict__ out, int mode)
{
  __shared__ h16 XL[64*XLS];               // 46,080 B
  const int n = blockIdx.x;
  const int t = threadIdx.x;
  // stage X: XL[b][m*66+d] = Xh[m-plane][n][b][d], d<66; pad [330,352)=0
  {
    const unsigned int* src = (const unsigned int*)Xh;
    unsigned int* dstu = (unsigned int*)XL;
    const size_t nbase = (size_t)n*(WROW/2);
    for (int i = t; i < 10560; i += 256) {      // 64b * 5m * 33 uints
      int b = i / 165, rem = i - b*165;
      int m = rem / 33, du = rem - m*33;
      dstu[b*(XLS/2) + m*33 + du] =
          src[(size_t)m*((size_t)N_NODES*(WROW/2)) + nbase + b*36 + du];
    }
    for (int i = t; i < 704; i += 256) {        // 64b * 11 pad uints
      int b = i / 11, du = i - b*11;
      dstu[b*(XLS/2) + 165 + du] = 0u;
    }
  }
  __syncthreads();

  const int w = t >> 6, lane = t & 63;
  const int quad = lane >> 4, lr = lane & 15;
  const int b0 = w*16;
  const int nt = mode ? 4 : 8;
  f32x4 acc[8];
  #pragma unroll
  for (int i = 0; i < 8; ++i) acc[i] = (f32x4){0.f,0.f,0.f,0.f};

  const f16x8* wbase = (const f16x8*)Wz + lane;
  for (int k0 = 0; k0 < 11; ++k0) {
    f16x8 a = *(const f16x8*)(XL + (b0 + lr)*XLS + k0*32 + quad*8);
    const f16x8* wk = wbase + (size_t)k0*64;
    for (int ot = 0; ot < nt; ++ot) {
      f16x8 bf = wk[(size_t)ot*704];           // (ot*11+k0)*64 + lane
      acc[ot] = __builtin_amdgcn_mfma_f32_16x16x32_f16(a, bf, acc[ot], 0, 0, 0);
    }
  }

  if (mode == 0) {
    for (int ot = 0; ot < 8; ++ot) {
      int o = ot*16 + lr;
      float bia = bias[o];
      #pragma unroll
      for (int r = 0; r < 4; ++r) {
        int b = b0 + quad*4 + r;
        float v = acc[ot][r] + bia;
        VAL[((size_t)b*N_NODES + n)*128 + o] = __float2half_rn(1.f/(1.f + expf(-v)));
      }
    }
  } else {
    for (int ot = 0; ot < 4; ++ot) {
      int o = ot*16 + lr;
      float bia = bias[o];
      #pragma unroll
      for (int r = 0; r < 4; ++r) {
        int b = b0 + quad*4 + r;
        float cc = tanhf(acc[ot][r] + bia);
        float u  = __half2float(VALu[((size_t)b*N_NODES + n)*128 + 64 + o]);
        float h  = hx[(size_t)b*(N_NODES*64) + n*64 + o];
        out[(size_t)b*(N_NODES*64) + n*64 + o] = u*h + (1.f - u)*cc;
      }
    }
  }
}

extern "C" void kernel_launch(void* const* d_in, const int* in_sizes, int n_in,
                              void* d_out, int out_size, void* d_ws, size_t ws_size,
                              hipStream_t stream)
{
  const float* inp      = (const float*)d_in[0];
  const float* hx       = (const float*)d_in[1];
  const float* supp     = (const float*)d_in[2];
  const float* mu_w_ru  = (const float*)d_in[3];
  const float* ls_w_ru  = (const float*)d_in[4];
  const float* mu_b_ru  = (const float*)d_in[5];
  const float* ls_b_ru  = (const float*)d_in[6];
  const float* eps_w_ru = (const float*)d_in[7];
  const float* eps_b_ru = (const float*)d_in[8];
  const float* mu_w_c   = (const float*)d_in[9];
  const float* ls_w_c   = (const float*)d_in[10];
  const float* mu_b_c   = (const float*)d_in[11];
  const float* ls_b_c   = (const float*)d_in[12];
  const float* eps_w_c  = (const float*)d_in[13];
  const float* eps_b_c  = (const float*)d_in[14];
  float* out = (float*)d_out;

  char* wsp = (char*)d_ws;
  size_t off = 0;
  auto take = [&](size_t bytes) -> void* {
    void* p = wsp + off;
    off = (off + bytes + 255) & ~(size_t)255;
    return p;
  };
  const size_t NSF = (size_t)N_NODES * WROW;                 // 9,216,000
  h16*   Xh  = (h16*)  take(5*NSF*sizeof(h16));              //  92.2 MB
  h16*   VAL = (h16*)  take((size_t)BATCH*N_NODES*128*sizeof(h16)); // 32.8 MB
  h16*   Wzru= (h16*)  take((size_t)8*11*64*8*sizeof(h16));  // 90 KB
  h16*   Wzc = (h16*)  take((size_t)4*11*64*8*sizeof(h16));  // 45 KB
  float* bru = (float*)take(128*sizeof(float));
  float* bc  = (float*)take(64*sizeof(float));
  unsigned short* ellc = (unsigned short*)take((size_t)2*N_NODES*ELLW*sizeof(unsigned short));
  float* ellv= (float*)take((size_t)2*N_NODES*ELLW*sizeof(float));
  int*   cnt = (int*)  take((size_t)2*N_NODES*sizeof(int));
  // total ~128.5 MB (R5/R6 ran at this footprint)
  (void)ws_size;

  hipMemsetAsync(cnt, 0, (size_t)2*N_NODES*sizeof(int), stream);
  k_weights<<<265, 256, 0, stream>>>(mu_w_ru, ls_w_ru, eps_w_ru,
                                     mu_b_ru, ls_b_ru, eps_b_ru,
                                     mu_w_c, ls_w_c, eps_w_c,
                                     mu_b_c, ls_b_c, eps_b_c,
                                     Wzru, bru, Wzc, bc);
  k_ell<<<dim3(8, N_NODES, 2), 256, 0, stream>>>(supp, ellc, ellv, cnt);

  h16* X0 = Xh;
  h16* X1 = Xh +   NSF;
  h16* X2 = Xh + 2*NSF;
  h16* X3 = Xh + 3*NSF;
  h16* X4 = Xh + 4*NSF;

  for (int pass = 0; pass < 2; ++pass) {
    k_build0<<<N_NODES, 256, 0, stream>>>(inp, hx, VAL, X0, pass);
    k_spmm <<<dim3(N_NODES, 2), 256, 0, stream>>>(X1, X3, X0, ellc, ellv, cnt);
    k_cheb <<<dim3(N_NODES, 2), 256, 0, stream>>>(X2, X4, X1, X3, X0, ellc, ellv, cnt);
    if (pass == 0)
      k_projm<<<N_NODES, 256, 0, stream>>>(Xh, Wzru, bru, VAL,
                                           nullptr, nullptr, nullptr, 0);
    else
      k_projm<<<N_NODES, 256, 0, stream>>>(Xh, Wzc, bc, nullptr,
                                           hx, VAL, out, 1);
  }
}

// Round 8
// 703.482 us; speedup vs baseline: 1.5283x; 1.2533x over previous
//
#include <hip/hip_runtime.h>
#include <hip/hip_fp16.h>

// RandDCGRUCell on MI355X.
// B=64, N=2000, IN_DIM=2, U=64, D=66, NSUP=2, K=2, M=5.
// R7: MFMA projection (882 us). Bottleneck moved to SpMM gathers:
// k_cheb/k_spmm ~126 us each, FETCH 400 MB vs 18.4 MB plane (L2 thrash:
// whole-plane gather working set >> 4 MB per-XCD L2).
// R8: batch split into 8 chunks of 8 (slice = 2000x576 halfs = 2.3 MB,
// L2-resident), chunk pinned to XCD via blockIdx.x (linear%8 round-robin).
// X planes stored chunk-major [cc][n][bsub][72]. Gathers: 32-lane groups,
// 9 dword loads/lane. Nontemporal for dst stores + cheb x0 operand so the
// gather slice stays hot. Numerics identical to R7.

#define N_NODES 2000
#define BATCH   64
#define DFEAT   66
#define DPAD    72           // halfs per (b) row
#define WROW    (BATCH*DPAD) // 4608 halfs per (n, matrix)
#define MMATS   5
#define ELLW    128
#define XLS     360          // LDS row stride in halfs (180 dwords, bank-safe)
#define SLICE_U (N_NODES*288)   // uints per chunk slice per plane (576,000)
#define SLICE_H (N_NODES*576)   // halfs per chunk slice per plane
#define PLANE_U (N_NODES*2304)  // uints per plane (4,608,000)

typedef __half h16;
typedef _Float16 f16x8 __attribute__((ext_vector_type(8)));
typedef float    f32x4 __attribute__((ext_vector_type(4)));

__device__ __forceinline__ __half2 f2h2(float a, float b) {
  __half2 r; r.x = __float2half_rn(a); r.y = __float2half_rn(b); return r;
}
__device__ __forceinline__ unsigned int packh(float a, float b) {
  __half2 h = f2h2(a, b);
  return __builtin_bit_cast(unsigned int, h);
}
__device__ __forceinline__ float2 u2f2(unsigned int u) {
  return __half22float2(__builtin_bit_cast(__half2, u));
}

// ---------------- weights: fragment-order swizzled fp16 W -----------
// Wz[((ot*11 + k0)*64 + lane)*8 + j] = W[k][o],  k = k0*32 + (lane>>4)*8 + j,
// o = ot*16 + (lane&15), k-order k = m*66+d, original row = d*5+m, k>=330 -> 0.
__global__ __launch_bounds__(256) void k_weights(
    const float* __restrict__ mu_w_ru, const float* __restrict__ ls_w_ru, const float* __restrict__ eps_w_ru,
    const float* __restrict__ mu_b_ru, const float* __restrict__ ls_b_ru, const float* __restrict__ eps_b_ru,
    const float* __restrict__ mu_w_c,  const float* __restrict__ ls_w_c,  const float* __restrict__ eps_w_c,
    const float* __restrict__ mu_b_c,  const float* __restrict__ ls_b_c,  const float* __restrict__ eps_b_c,
    h16* __restrict__ Wzru, float* __restrict__ bru,
    h16* __restrict__ Wzc,  float* __restrict__ bc)
{
  int idx = blockIdx.x*256 + threadIdx.x;
  const int n_ru = 8*11*64*8;   // 45056
  const int n_c  = 4*11*64*8;   // 22528
  if (idx < n_ru) {
    int j = idx & 7, ln = (idx >> 3) & 63, rest = idx >> 9;
    int k = (rest % 11)*32 + (ln >> 4)*8 + j;
    int o = (rest / 11)*16 + (ln & 15);
    float wv = 0.f;
    if (k < 330) {
      int m = k/66, d = k - m*66;
      int r = (d*MMATS + m)*128 + o;
      wv = mu_w_ru[r] + expf(ls_w_ru[r]) * eps_w_ru[r];
    }
    Wzru[idx] = __float2half_rn(wv);
  } else if (idx < n_ru + n_c) {
    int i = idx - n_ru;
    int j = i & 7, ln = (i >> 3) & 63, rest = i >> 9;
    int k = (rest % 11)*32 + (ln >> 4)*8 + j;
    int o = (rest / 11)*16 + (ln & 15);
    float wv = 0.f;
    if (k < 330) {
      int m = k/66, d = k - m*66;
      int r = (d*MMATS + m)*64 + o;
      wv = mu_w_c[r] + expf(ls_w_c[r]) * eps_w_c[r];
    }
    Wzc[i] = __float2half_rn(wv);
  } else if (idx < n_ru + n_c + 128) {
    int i = idx - n_ru - n_c;
    bru[i] = mu_b_ru[i] + expf(ls_b_ru[i]) * eps_b_ru[i];
  } else if (idx < n_ru + n_c + 128 + 64) {
    int i = idx - n_ru - n_c - 128;
    bc[i] = mu_b_c[i] + expf(ls_b_c[i]) * eps_b_c[i];
  }
}

// ---------------- ELL build (order within row irrelevant for a sum) --
__global__ __launch_bounds__(256) void k_ell(
    const float* __restrict__ supp, unsigned short* __restrict__ cols,
    float* __restrict__ vals, int* __restrict__ cnt)
{
  int j = blockIdx.x*256 + threadIdx.x;
  if (j >= N_NODES) return;
  int n = blockIdx.y, s = blockIdx.z;
  int r = s*N_NODES + n;
  float v = supp[(size_t)r*N_NODES + j];
  if (v != 0.f) {
    int p = atomicAdd(cnt + r, 1);
    if (p < ELLW) {
      cols[(size_t)r*ELLW + p] = (unsigned short)j;
      vals[(size_t)r*ELLW + p] = v;
    }
  }
}

// ---------------- build x0 chunk-major fp16 -------------------------
// X plane layout: [cc][n][bsub][DPAD], cc = b>>3, bsub = b&7.
__global__ __launch_bounds__(256) void k_build0(
    const float* __restrict__ inp, const float* __restrict__ hx,
    const h16* __restrict__ VALr, h16* __restrict__ xb, int mode)
{
  int n = blockIdx.x;
  for (int idx = threadIdx.x; idx < WROW; idx += 256) {
    int b = idx / DPAD, d = idx % DPAD;
    float v = 0.f;
    if (d < 2) {
      v = inp[(size_t)b*(N_NODES*2) + n*2 + d];
    } else if (d < DFEAT) {
      float hv = hx[(size_t)b*(N_NODES*64) + n*64 + (d-2)];
      if (mode == 1) hv *= __half2float(VALr[((size_t)b*N_NODES + n)*128 + (d-2)]); // r gate
      v = hv;
    }
    int cc = b >> 3, bs = b & 7;
    xb[(size_t)cc*SLICE_H + (size_t)n*576 + bs*72 + d] = __float2half_rn(v);
  }
}

// ---------------- SpMM: x1 = S @ x0 (both supports, chunk slices) ----
// grid (8 chunks, 500); block 256 = 8 groups of 32; group g -> row r.
__global__ __launch_bounds__(256) void k_spmm(
    h16* __restrict__ dst0, h16* __restrict__ dst1,
    const h16* __restrict__ src, const unsigned short* __restrict__ cols,
    const float* __restrict__ vals, const int* __restrict__ cnt)
{
  const int cc = blockIdx.x;
  const int r  = blockIdx.y*8 + (threadIdx.x >> 5);
  const int tt = threadIdx.x & 31;
  const int s  = (r >= N_NODES) ? 1 : 0;
  const int n  = r - s*N_NODES;
  int c = cnt[r]; if (c > ELLW) c = ELLW;
  const unsigned short* cp = cols + (size_t)r*ELLW;
  const float*          vp = vals + (size_t)r*ELLW;
  const unsigned int* slice = (const unsigned int*)src + (size_t)cc*SLICE_U;
  float2 acc[9];
  #pragma unroll
  for (int i = 0; i < 9; ++i) acc[i] = make_float2(0.f, 0.f);
  for (int k = 0; k < c; ++k) {
    int j = cp[k]; float v = vp[k];
    const unsigned int* s0 = slice + (size_t)j*288 + tt;
    #pragma unroll
    for (int i = 0; i < 9; ++i) {
      float2 f = u2f2(s0[i*32]);
      acc[i].x = fmaf(v, f.x, acc[i].x);
      acc[i].y = fmaf(v, f.y, acc[i].y);
    }
  }
  unsigned int* dp = (unsigned int*)(s ? dst1 : dst0)
                   + (size_t)cc*SLICE_U + (size_t)n*288 + tt;
  #pragma unroll
  for (int i = 0; i < 9; ++i)
    __builtin_nontemporal_store(packh(acc[i].x, acc[i].y), dp + i*32);
}

// ---------------- Chebyshev: x2 = 2*(S @ x1) - x0 --------------------
__global__ __launch_bounds__(256) void k_cheb(
    h16* __restrict__ dst0, h16* __restrict__ dst1,
    const h16* __restrict__ src0, const h16* __restrict__ src1,
    const h16* __restrict__ x0, const unsigned short* __restrict__ cols,
    const float* __restrict__ vals, const int* __restrict__ cnt)
{
  const int cc = blockIdx.x;
  const int r  = blockIdx.y*8 + (threadIdx.x >> 5);
  const int tt = threadIdx.x & 31;
  const int s  = (r >= N_NODES) ? 1 : 0;
  const int n  = r - s*N_NODES;
  int c = cnt[r]; if (c > ELLW) c = ELLW;
  const unsigned short* cp = cols + (size_t)r*ELLW;
  const float*          vp = vals + (size_t)r*ELLW;
  const unsigned int* slice = (const unsigned int*)(s ? src1 : src0)
                            + (size_t)cc*SLICE_U;
  float2 acc[9];
  #pragma unroll
  for (int i = 0; i < 9; ++i) acc[i] = make_float2(0.f, 0.f);
  for (int k = 0; k < c; ++k) {
    int j = cp[k]; float v = vp[k];
    const unsigned int* s0 = slice + (size_t)j*288 + tt;
    #pragma unroll
    for (int i = 0; i < 9; ++i) {
      float2 f = u2f2(s0[i*32]);
      acc[i].x = fmaf(v, f.x, acc[i].x);
      acc[i].y = fmaf(v, f.y, acc[i].y);
    }
  }
  const unsigned int* xp = (const unsigned int*)x0
                         + (size_t)cc*SLICE_U + (size_t)n*288 + tt;
  unsigned int* dp = (unsigned int*)(s ? dst1 : dst0)
                   + (size_t)cc*SLICE_U + (size_t)n*288 + tt;
  #pragma unroll
  for (int i = 0; i < 9; ++i) {
    float2 f0 = u2f2(__builtin_nontemporal_load(xp + i*32));
    __builtin_nontemporal_store(packh(2.f*acc[i].x - f0.x, 2.f*acc[i].y - f0.y),
                                dp + i*32);
  }
}

// ---------------- projection via MFMA 16x16x32 f16 -------------------
// Per block: node n, C[64b x (nt*16)o] = XL[64 x 352] * Wz[352 x nt*16].
// mode 0: VAL[b][n][o] = sigmoid(acc+bias) fp16  (nt=8, o in [0,128))
// mode 1: out = u*hx + (1-u)*tanh(acc+bias) fp32 (nt=4, o in [0,64))
__global__ __launch_bounds__(256) void k_projm(
    const h16* __restrict__ Xh, const h16* __restrict__ Wz,
    const float* __restrict__ bias, h16* __restrict__ VAL,
    const float* __restrict__ hx, const h16* __restrict__ VALu,
    float* __restrict__ out, int mode)
{
  __shared__ h16 XL[64*XLS];               // 46,080 B
  const int n = blockIdx.x;
  const int t = threadIdx.x;
  // stage X: XL[b][m*66+d] = plane m, chunk b>>3, bsub b&7; pad [330,352)=0
  {
    const unsigned int* src = (const unsigned int*)Xh;
    unsigned int* dstu = (unsigned int*)XL;
    for (int i = t; i < 10560; i += 256) {      // 64b * 5m * 33 uints
      int b = i / 165, rem = i - b*165;
      int m = rem / 33, du = rem - m*33;
      int cc = b >> 3, bs = b & 7;
      dstu[b*(XLS/2) + m*33 + du] =
          src[(size_t)m*PLANE_U + (size_t)cc*SLICE_U + (size_t)n*288 + bs*36 + du];
    }
    for (int i = t; i < 704; i += 256) {        // 64b * 11 pad uints
      int b = i / 11, du = i - b*11;
      dstu[b*(XLS/2) + 165 + du] = 0u;
    }
  }
  __syncthreads();

  const int w = t >> 6, lane = t & 63;
  const int quad = lane >> 4, lr = lane & 15;
  const int b0 = w*16;
  const int nt = mode ? 4 : 8;
  f32x4 acc[8];
  #pragma unroll
  for (int i = 0; i < 8; ++i) acc[i] = (f32x4){0.f,0.f,0.f,0.f};

  const f16x8* wbase = (const f16x8*)Wz + lane;
  for (int k0 = 0; k0 < 11; ++k0) {
    f16x8 a = *(const f16x8*)(XL + (b0 + lr)*XLS + k0*32 + quad*8);
    const f16x8* wk = wbase + (size_t)k0*64;
    for (int ot = 0; ot < nt; ++ot) {
      f16x8 bf = wk[(size_t)ot*704];           // (ot*11+k0)*64 + lane
      acc[ot] = __builtin_amdgcn_mfma_f32_16x16x32_f16(a, bf, acc[ot], 0, 0, 0);
    }
  }

  if (mode == 0) {
    for (int ot = 0; ot < 8; ++ot) {
      int o = ot*16 + lr;
      float bia = bias[o];
      #pragma unroll
      for (int r = 0; r < 4; ++r) {
        int b = b0 + quad*4 + r;
        float v = acc[ot][r] + bia;
        VAL[((size_t)b*N_NODES + n)*128 + o] = __float2half_rn(1.f/(1.f + expf(-v)));
      }
    }
  } else {
    for (int ot = 0; ot < 4; ++ot) {
      int o = ot*16 + lr;
      float bia = bias[o];
      #pragma unroll
      for (int r = 0; r < 4; ++r) {
        int b = b0 + quad*4 + r;
        float cc = tanhf(acc[ot][r] + bia);
        float u  = __half2float(VALu[((size_t)b*N_NODES + n)*128 + 64 + o]);
        float h  = hx[(size_t)b*(N_NODES*64) + n*64 + o];
        out[(size_t)b*(N_NODES*64) + n*64 + o] = u*h + (1.f - u)*cc;
      }
    }
  }
}

extern "C" void kernel_launch(void* const* d_in, const int* in_sizes, int n_in,
                              void* d_out, int out_size, void* d_ws, size_t ws_size,
                              hipStream_t stream)
{
  const float* inp      = (const float*)d_in[0];
  const float* hx       = (const float*)d_in[1];
  const float* supp     = (const float*)d_in[2];
  const float* mu_w_ru  = (const float*)d_in[3];
  const float* ls_w_ru  = (const float*)d_in[4];
  const float* mu_b_ru  = (const float*)d_in[5];
  const float* ls_b_ru  = (const float*)d_in[6];
  const float* eps_w_ru = (const float*)d_in[7];
  const float* eps_b_ru = (const float*)d_in[8];
  const float* mu_w_c   = (const float*)d_in[9];
  const float* ls_w_c   = (const float*)d_in[10];
  const float* mu_b_c   = (const float*)d_in[11];
  const float* ls_b_c   = (const float*)d_in[12];
  const float* eps_w_c  = (const float*)d_in[13];
  const float* eps_b_c  = (const float*)d_in[14];
  float* out = (float*)d_out;

  char* wsp = (char*)d_ws;
  size_t off = 0;
  auto take = [&](size_t bytes) -> void* {
    void* p = wsp + off;
    off = (off + bytes + 255) & ~(size_t)255;
    return p;
  };
  const size_t NSF = (size_t)N_NODES * WROW;                 // 9,216,000
  h16*   Xh  = (h16*)  take(5*NSF*sizeof(h16));              //  92.2 MB
  h16*   VAL = (h16*)  take((size_t)BATCH*N_NODES*128*sizeof(h16)); // 32.8 MB
  h16*   Wzru= (h16*)  take((size_t)8*11*64*8*sizeof(h16));  // 90 KB
  h16*   Wzc = (h16*)  take((size_t)4*11*64*8*sizeof(h16));  // 45 KB
  float* bru = (float*)take(128*sizeof(float));
  float* bc  = (float*)take(64*sizeof(float));
  unsigned short* ellc = (unsigned short*)take((size_t)2*N_NODES*ELLW*sizeof(unsigned short));
  float* ellv= (float*)take((size_t)2*N_NODES*ELLW*sizeof(float));
  int*   cnt = (int*)  take((size_t)2*N_NODES*sizeof(int));
  // total ~128.5 MB (R5-R7 ran at this footprint)
  (void)ws_size;

  hipMemsetAsync(cnt, 0, (size_t)2*N_NODES*sizeof(int), stream);
  k_weights<<<265, 256, 0, stream>>>(mu_w_ru, ls_w_ru, eps_w_ru,
                                     mu_b_ru, ls_b_ru, eps_b_ru,
                                     mu_w_c, ls_w_c, eps_w_c,
                                     mu_b_c, ls_b_c, eps_b_c,
                                     Wzru, bru, Wzc, bc);
  k_ell<<<dim3(8, N_NODES, 2), 256, 0, stream>>>(supp, ellc, ellv, cnt);

  h16* X0 = Xh;
  h16* X1 = Xh +   NSF;
  h16* X2 = Xh + 2*NSF;
  h16* X3 = Xh + 3*NSF;
  h16* X4 = Xh + 4*NSF;

  for (int pass = 0; pass < 2; ++pass) {
    k_build0<<<N_NODES, 256, 0, stream>>>(inp, hx, VAL, X0, pass);
    k_spmm <<<dim3(8, 500), 256, 0, stream>>>(X1, X3, X0, ellc, ellv, cnt);
    k_cheb <<<dim3(8, 500), 256, 0, stream>>>(X2, X4, X1, X3, X0, ellc, ellv, cnt);
    if (pass == 0)
      k_projm<<<N_NODES, 256, 0, stream>>>(Xh, Wzru, bru, VAL,
                                           nullptr, nullptr, nullptr, 0);
    else
      k_projm<<<N_NODES, 256, 0, stream>>>(Xh, Wzc, bc, nullptr,
                                           hx, VAL, out, 1);
  }
}

// Round 9
// 664.784 us; speedup vs baseline: 1.6173x; 1.0582x over previous
//
#include <hip/hip_runtime.h>
#include <hip/hip_fp16.h>

// RandDCGRUCell on MI355X.
// B=64, N=2000, IN_DIM=2, U=64, D=66, NSUP=2, K=2, M=5.
// R8 post-mortem: k_projm = 138 us, MfmaUtil 3%, VALU 35%, occ 29% ->
// latency-bound LDS staging, not MFMA. R9: X arena stored in MFMA-A-fragment
// micro-block layout [cc][n][kb][bs][8k] (kb = 8-half K-block; plane p = kbs
// 9p..9p+8; K 360 padded to 384). SpMM/cheb are element-wise transparent to
// the K-permutation (same 9xdword gather loop, new base math). k_projm:
// ZERO LDS, no barrier, direct coalesced A-frag loads. VAL -> [n][b][128].

#define N_NODES 2000
#define BATCH   64
#define MMATS   5
#define ELLW    128
#define NSTRIDE 1536            // dwords per (cc, n): 48 kb * 32
#define SLICE_DW ((size_t)N_NODES * NSTRIDE)   // dwords per chunk (3,072,000)
#define PLANE_OFF(p) ((p)*288)  // dword offset of plane p within (cc,n)

typedef __half h16;
typedef _Float16 f16x8 __attribute__((ext_vector_type(8)));
typedef float    f32x4 __attribute__((ext_vector_type(4)));

__device__ __forceinline__ __half2 f2h2(float a, float b) {
  __half2 r; r.x = __float2half_rn(a); r.y = __float2half_rn(b); return r;
}
__device__ __forceinline__ unsigned int packh(float a, float b) {
  __half2 h = f2h2(a, b);
  return __builtin_bit_cast(unsigned int, h);
}
__device__ __forceinline__ float2 u2f2(unsigned int u) {
  return __half22float2(__builtin_bit_cast(__half2, u));
}

// ---------------- weights: fragment-order swizzled fp16 W -----------
// Wz[((ot*12 + k0)*64 + lane)*8 + j] = W[k][o], k = k0*32 + (lane>>4)*8 + j,
// o = ot*16 + (lane&15); k = 72p + d (plane-major), d<66 valid, k>=360 -> 0.
__global__ __launch_bounds__(256) void k_weights(
    const float* __restrict__ mu_w_ru, const float* __restrict__ ls_w_ru, const float* __restrict__ eps_w_ru,
    const float* __restrict__ mu_b_ru, const float* __restrict__ ls_b_ru, const float* __restrict__ eps_b_ru,
    const float* __restrict__ mu_w_c,  const float* __restrict__ ls_w_c,  const float* __restrict__ eps_w_c,
    const float* __restrict__ mu_b_c,  const float* __restrict__ ls_b_c,  const float* __restrict__ eps_b_c,
    h16* __restrict__ Wzru, float* __restrict__ bru,
    h16* __restrict__ Wzc,  float* __restrict__ bc)
{
  int idx = blockIdx.x*256 + threadIdx.x;
  const int n_ru = 8*12*64*8;   // 49152
  const int n_c  = 4*12*64*8;   // 24576
  if (idx < n_ru) {
    int j = idx & 7, ln = (idx >> 3) & 63, rest = idx >> 9;
    int k = (rest % 12)*32 + (ln >> 4)*8 + j;
    int o = (rest / 12)*16 + (ln & 15);
    float wv = 0.f;
    if (k < 360) {
      int p = k/72, d = k - p*72;
      if (d < 66) {
        int r = (d*MMATS + p)*128 + o;
        wv = mu_w_ru[r] + expf(ls_w_ru[r]) * eps_w_ru[r];
      }
    }
    Wzru[idx] = __float2half_rn(wv);
  } else if (idx < n_ru + n_c) {
    int i = idx - n_ru;
    int j = i & 7, ln = (i >> 3) & 63, rest = i >> 9;
    int k = (rest % 12)*32 + (ln >> 4)*8 + j;
    int o = (rest / 12)*16 + (ln & 15);
    float wv = 0.f;
    if (k < 360) {
      int p = k/72, d = k - p*72;
      if (d < 66) {
        int r = (d*MMATS + p)*64 + o;
        wv = mu_w_c[r] + expf(ls_w_c[r]) * eps_w_c[r];
      }
    }
    Wzc[i] = __float2half_rn(wv);
  } else if (idx < n_ru + n_c + 128) {
    int i = idx - n_ru - n_c;
    bru[i] = mu_b_ru[i] + expf(ls_b_ru[i]) * eps_b_ru[i];
  } else if (idx < n_ru + n_c + 128 + 64) {
    int i = idx - n_ru - n_c - 128;
    bc[i] = mu_b_c[i] + expf(ls_b_c[i]) * eps_b_c[i];
  }
}

// ---------------- ELL build (order within row irrelevant for a sum) --
__global__ __launch_bounds__(256) void k_ell(
    const float* __restrict__ supp, unsigned short* __restrict__ cols,
    float* __restrict__ vals, int* __restrict__ cnt)
{
  int j = blockIdx.x*256 + threadIdx.x;
  if (j >= N_NODES) return;
  int n = blockIdx.y, s = blockIdx.z;
  int r = s*N_NODES + n;
  float v = supp[(size_t)r*N_NODES + j];
  if (v != 0.f) {
    int p = atomicAdd(cnt + r, 1);
    if (p < ELLW) {
      cols[(size_t)r*ELLW + p] = (unsigned short)j;
      vals[(size_t)r*ELLW + p] = v;
    }
  }
}

// ---------------- build x0 plane (p=0) + zero pad blocks -------------
// XA micro-block layout per (cc,n): [48kb][8bs][8k] halfs (1536 dwords).
// Group g (32 lanes) handles cc=g: dword kb*32+tt, bs=tt>>2, k=kb*8+2(tt&3).
__global__ __launch_bounds__(256) void k_build0(
    const float* __restrict__ inp, const float* __restrict__ hx,
    const h16* __restrict__ VALr, unsigned int* __restrict__ XAu, int mode)
{
  const int n = blockIdx.x;
  const int g = threadIdx.x >> 5, tt = threadIdx.x & 31;
  const int b = g*8 + (tt >> 2);
  unsigned int* dst = XAu + (size_t)g*SLICE_DW + (size_t)n*NSTRIDE;
  #pragma unroll
  for (int kb = 0; kb < 9; ++kb) {
    int d0 = kb*8 + 2*(tt & 3);
    float v[2];
    #pragma unroll
    for (int q = 0; q < 2; ++q) {
      int d = d0 + q;
      float x = 0.f;
      if (d < 2) {
        x = inp[(size_t)b*(N_NODES*2) + n*2 + d];
      } else if (d < 66) {
        x = hx[(size_t)b*(N_NODES*64) + n*64 + (d-2)];
        if (mode == 1) x *= __half2float(VALr[(size_t)n*8192 + b*128 + (d-2)]);
      }
      v[q] = x;
    }
    dst[kb*32 + tt] = packh(v[0], v[1]);
  }
  dst[45*32 + tt] = 0u;  // pad kbs 45..47 (k in [360,384))
  dst[46*32 + tt] = 0u;
  dst[47*32 + tt] = 0u;
}

// ---------------- SpMM: plane(1+2s) = S_s @ plane0 -------------------
__global__ __launch_bounds__(256) void k_spmm(
    unsigned int* __restrict__ XAu, const unsigned short* __restrict__ cols,
    const float* __restrict__ vals, const int* __restrict__ cnt)
{
  const int cc = blockIdx.x;
  const int r  = blockIdx.y*8 + (threadIdx.x >> 5);
  const int tt = threadIdx.x & 31;
  const int s  = (r >= N_NODES) ? 1 : 0;
  const int n  = r - s*N_NODES;
  int c = cnt[r]; if (c > ELLW) c = ELLW;
  const unsigned short* cp = cols + (size_t)r*ELLW;
  const float*          vp = vals + (size_t)r*ELLW;
  const unsigned int* slice = XAu + (size_t)cc*SLICE_DW;   // plane 0 offset 0
  float2 acc[9];
  #pragma unroll
  for (int i = 0; i < 9; ++i) acc[i] = make_float2(0.f, 0.f);
  for (int k = 0; k < c; ++k) {
    int j = cp[k]; float v = vp[k];
    const unsigned int* s0 = slice + (size_t)j*NSTRIDE + tt;
    #pragma unroll
    for (int i = 0; i < 9; ++i) {
      float2 f = u2f2(s0[i*32]);
      acc[i].x = fmaf(v, f.x, acc[i].x);
      acc[i].y = fmaf(v, f.y, acc[i].y);
    }
  }
  unsigned int* dp = XAu + (size_t)cc*SLICE_DW + (size_t)n*NSTRIDE
                   + PLANE_OFF(1 + 2*s) + tt;
  #pragma unroll
  for (int i = 0; i < 9; ++i)
    __builtin_nontemporal_store(packh(acc[i].x, acc[i].y), dp + i*32);
}

// ---------------- Chebyshev: plane(2+2s) = 2*S_s@plane(1+2s) - plane0 -
__global__ __launch_bounds__(256) void k_cheb(
    unsigned int* __restrict__ XAu, const unsigned short* __restrict__ cols,
    const float* __restrict__ vals, const int* __restrict__ cnt)
{
  const int cc = blockIdx.x;
  const int r  = blockIdx.y*8 + (threadIdx.x >> 5);
  const int tt = threadIdx.x & 31;
  const int s  = (r >= N_NODES) ? 1 : 0;
  const int n  = r - s*N_NODES;
  int c = cnt[r]; if (c > ELLW) c = ELLW;
  const unsigned short* cp = cols + (size_t)r*ELLW;
  const float*          vp = vals + (size_t)r*ELLW;
  const unsigned int* slice = XAu + (size_t)cc*SLICE_DW + PLANE_OFF(1 + 2*s);
  float2 acc[9];
  #pragma unroll
  for (int i = 0; i < 9; ++i) acc[i] = make_float2(0.f, 0.f);
  for (int k = 0; k < c; ++k) {
    int j = cp[k]; float v = vp[k];
    const unsigned int* s0 = slice + (size_t)j*NSTRIDE + tt;
    #pragma unroll
    for (int i = 0; i < 9; ++i) {
      float2 f = u2f2(s0[i*32]);
      acc[i].x = fmaf(v, f.x, acc[i].x);
      acc[i].y = fmaf(v, f.y, acc[i].y);
    }
  }
  const unsigned int* xp = XAu + (size_t)cc*SLICE_DW + (size_t)n*NSTRIDE + tt; // plane 0
  unsigned int* dp = XAu + (size_t)cc*SLICE_DW + (size_t)n*NSTRIDE
                   + PLANE_OFF(2 + 2*s) + tt;
  #pragma unroll
  for (int i = 0; i < 9; ++i) {
    float2 f0 = u2f2(__builtin_nontemporal_load(xp + i*32));
    __builtin_nontemporal_store(packh(2.f*acc[i].x - f0.x, 2.f*acc[i].y - f0.y),
                                dp + i*32);
  }
}

// ---------------- projection via MFMA 16x16x32 f16, LDS-free ---------
// Per block: node n. Wave w owns b-rows [16w,16w+16); 12 K-steps.
// A-frag: lane(quad,lr) loads f16x8 at [cc][n][kb=k0*4+quad][bs][8].
// mode 0: VAL[n][b][o] = sigmoid(acc+bias) fp16  (nt=8)
// mode 1: out = u*hx + (1-u)*tanh(acc+bias) fp32 (nt=4)
__global__ __launch_bounds__(256) void k_projm(
    const unsigned int* __restrict__ XAu, const h16* __restrict__ Wz,
    const float* __restrict__ bias, h16* __restrict__ VAL,
    const float* __restrict__ hx, const h16* __restrict__ VALu,
    float* __restrict__ out, int mode)
{
  const int n = blockIdx.x;
  const int t = threadIdx.x;
  const int w = t >> 6, lane = t & 63;
  const int quad = lane >> 4, lr = lane & 15;
  const int b0 = w*16;
  const int cc = 2*w + (lr >> 3), bs = lr & 7;
  const int nt = mode ? 4 : 8;

  f32x4 acc[8];
  #pragma unroll
  for (int i = 0; i < 8; ++i) acc[i] = (f32x4){0.f,0.f,0.f,0.f};

  const h16* abase = (const h16*)(XAu + (size_t)cc*SLICE_DW + (size_t)n*NSTRIDE)
                   + bs*8 + quad*64;
  const f16x8* wbase = (const f16x8*)Wz + lane;
  for (int k0 = 0; k0 < 12; ++k0) {
    f16x8 a = *(const f16x8*)(abase + k0*256);
    const f16x8* wk = wbase + (size_t)k0*64;
    for (int ot = 0; ot < nt; ++ot) {
      f16x8 bf = wk[(size_t)ot*768];           // ((ot*12+k0)*64 + lane)
      acc[ot] = __builtin_amdgcn_mfma_f32_16x16x32_f16(a, bf, acc[ot], 0, 0, 0);
    }
  }

  if (mode == 0) {
    for (int ot = 0; ot < 8; ++ot) {
      int o = ot*16 + lr;
      float bia = bias[o];
      #pragma unroll
      for (int r = 0; r < 4; ++r) {
        int b = b0 + quad*4 + r;
        float v = acc[ot][r] + bia;
        VAL[(size_t)n*8192 + b*128 + o] = __float2half_rn(1.f/(1.f + expf(-v)));
      }
    }
  } else {
    for (int ot = 0; ot < 4; ++ot) {
      int o = ot*16 + lr;
      float bia = bias[o];
      #pragma unroll
      for (int r = 0; r < 4; ++r) {
        int b = b0 + quad*4 + r;
        float cv = tanhf(acc[ot][r] + bia);
        float u  = __half2float(VALu[(size_t)n*8192 + b*128 + 64 + o]);
        float h  = hx[(size_t)b*(N_NODES*64) + n*64 + o];
        out[(size_t)b*(N_NODES*64) + n*64 + o] = u*h + (1.f - u)*cv;
      }
    }
  }
}

extern "C" void kernel_launch(void* const* d_in, const int* in_sizes, int n_in,
                              void* d_out, int out_size, void* d_ws, size_t ws_size,
                              hipStream_t stream)
{
  const float* inp      = (const float*)d_in[0];
  const float* hx       = (const float*)d_in[1];
  const float* supp     = (const float*)d_in[2];
  const float* mu_w_ru  = (const float*)d_in[3];
  const float* ls_w_ru  = (const float*)d_in[4];
  const float* mu_b_ru  = (const float*)d_in[5];
  const float* ls_b_ru  = (const float*)d_in[6];
  const float* eps_w_ru = (const float*)d_in[7];
  const float* eps_b_ru = (const float*)d_in[8];
  const float* mu_w_c   = (const float*)d_in[9];
  const float* ls_w_c   = (const float*)d_in[10];
  const float* mu_b_c   = (const float*)d_in[11];
  const float* ls_b_c   = (const float*)d_in[12];
  const float* eps_w_c  = (const float*)d_in[13];
  const float* eps_b_c  = (const float*)d_in[14];
  float* out = (float*)d_out;

  char* wsp = (char*)d_ws;
  size_t off = 0;
  auto take = [&](size_t bytes) -> void* {
    void* p = wsp + off;
    off = (off + bytes + 255) & ~(size_t)255;
    return p;
  };
  unsigned int* XAu = (unsigned int*)take(8*SLICE_DW*sizeof(unsigned int)); // 98.3 MB
  h16*   VAL = (h16*)  take((size_t)N_NODES*8192*sizeof(h16));       // 32.8 MB
  h16*   Wzru= (h16*)  take((size_t)8*12*64*8*sizeof(h16));          // 98.3 KB
  h16*   Wzc = (h16*)  take((size_t)4*12*64*8*sizeof(h16));          // 49.2 KB
  float* bru = (float*)take(128*sizeof(float));
  float* bc  = (float*)take(64*sizeof(float));
  unsigned short* ellc = (unsigned short*)take((size_t)2*N_NODES*ELLW*sizeof(unsigned short));
  float* ellv= (float*)take((size_t)2*N_NODES*ELLW*sizeof(float));
  int*   cnt = (int*)  take((size_t)2*N_NODES*sizeof(int));
  // total ~134.5 MB
  (void)ws_size;

  hipMemsetAsync(cnt, 0, (size_t)2*N_NODES*sizeof(int), stream);
  k_weights<<<289, 256, 0, stream>>>(mu_w_ru, ls_w_ru, eps_w_ru,
                                     mu_b_ru, ls_b_ru, eps_b_ru,
                                     mu_w_c, ls_w_c, eps_w_c,
                                     mu_b_c, ls_b_c, eps_b_c,
                                     Wzru, bru, Wzc, bc);
  k_ell<<<dim3(8, N_NODES, 2), 256, 0, stream>>>(supp, ellc, ellv, cnt);

  for (int pass = 0; pass < 2; ++pass) {
    k_build0<<<N_NODES, 256, 0, stream>>>(inp, hx, VAL, XAu, pass);
    k_spmm <<<dim3(8, 500), 256, 0, stream>>>(XAu, ellc, ellv, cnt);
    k_cheb <<<dim3(8, 500), 256, 0, stream>>>(XAu, ellc, ellv, cnt);
    if (pass == 0)
      k_projm<<<N_NODES, 256, 0, stream>>>(XAu, Wzru, bru, VAL,
                                           nullptr, nullptr, nullptr, 0);
    else
      k_projm<<<N_NODES, 256, 0, stream>>>(XAu, Wzc, bc, nullptr,
                                           hx, VAL, out, 1);
  }
}

// Round 10
// 627.049 us; speedup vs baseline: 1.7146x; 1.0602x over previous
//
#include <hip/hip_runtime.h>
#include <hip/hip_fp16.h>

// RandDCGRUCell on MI355X.
// B=64, N=2000, IN_DIM=2, U=64, D=66, NSUP=2, K=2, M=5.
// R9 post-mortem: k_projm 95 us with MfmaUtil 5%, VALU 36% -> epilogue was
// calling libm expf/tanhf (~25-40 instr + real divide) 32x/thread. Also
// k_spmm's nontemporal stores evicted planes 1/3 from L2, which k_cheb
// re-gathers ~31x. R10: (1) HW transcendentals (v_exp_f32 + v_rcp_f32)
// for sigmoid/tanh; (2) spmm stores regular (L2-hot for cheb); cheb keeps
// nt stores (planes 2/4 streamed) + nt x0 load. Numerics delta ~1e-6.

#define N_NODES 2000
#define BATCH   64
#define MMATS   5
#define ELLW    128
#define NSTRIDE 1536            // dwords per (cc, n): 48 kb * 32
#define SLICE_DW ((size_t)N_NODES * NSTRIDE)   // dwords per chunk (3,072,000)
#define PLANE_OFF(p) ((p)*288)  // dword offset of plane p within (cc,n)

typedef __half h16;
typedef _Float16 f16x8 __attribute__((ext_vector_type(8)));
typedef float    f32x4 __attribute__((ext_vector_type(4)));

__device__ __forceinline__ __half2 f2h2(float a, float b) {
  __half2 r; r.x = __float2half_rn(a); r.y = __float2half_rn(b); return r;
}
__device__ __forceinline__ unsigned int packh(float a, float b) {
  __half2 h = f2h2(a, b);
  return __builtin_bit_cast(unsigned int, h);
}
__device__ __forceinline__ float2 u2f2(unsigned int u) {
  return __half22float2(__builtin_bit_cast(__half2, u));
}
__device__ __forceinline__ float fexp2(float x) {
#if __has_builtin(__builtin_amdgcn_exp2f)
  return __builtin_amdgcn_exp2f(x);
#else
  return exp2f(x);
#endif
}
__device__ __forceinline__ float frcp(float x) {
#if __has_builtin(__builtin_amdgcn_rcpf)
  return __builtin_amdgcn_rcpf(x);
#else
  return 1.f/x;
#endif
}
#define LOG2E 1.44269504088896f
__device__ __forceinline__ float fsigmoid(float x) {
  return frcp(1.f + fexp2(-LOG2E*x));
}
__device__ __forceinline__ float ftanh(float x) {
  return 1.f - 2.f*frcp(1.f + fexp2((2.f*LOG2E)*x));
}

// ---------------- weights: fragment-order swizzled fp16 W -----------
// Wz[((ot*12 + k0)*64 + lane)*8 + j] = W[k][o], k = k0*32 + (lane>>4)*8 + j,
// o = ot*16 + (lane&15); k = 72p + d (plane-major), d<66 valid, k>=360 -> 0.
__global__ __launch_bounds__(256) void k_weights(
    const float* __restrict__ mu_w_ru, const float* __restrict__ ls_w_ru, const float* __restrict__ eps_w_ru,
    const float* __restrict__ mu_b_ru, const float* __restrict__ ls_b_ru, const float* __restrict__ eps_b_ru,
    const float* __restrict__ mu_w_c,  const float* __restrict__ ls_w_c,  const float* __restrict__ eps_w_c,
    const float* __restrict__ mu_b_c,  const float* __restrict__ ls_b_c,  const float* __restrict__ eps_b_c,
    h16* __restrict__ Wzru, float* __restrict__ bru,
    h16* __restrict__ Wzc,  float* __restrict__ bc)
{
  int idx = blockIdx.x*256 + threadIdx.x;
  const int n_ru = 8*12*64*8;   // 49152
  const int n_c  = 4*12*64*8;   // 24576
  if (idx < n_ru) {
    int j = idx & 7, ln = (idx >> 3) & 63, rest = idx >> 9;
    int k = (rest % 12)*32 + (ln >> 4)*8 + j;
    int o = (rest / 12)*16 + (ln & 15);
    float wv = 0.f;
    if (k < 360) {
      int p = k/72, d = k - p*72;
      if (d < 66) {
        int r = (d*MMATS + p)*128 + o;
        wv = mu_w_ru[r] + expf(ls_w_ru[r]) * eps_w_ru[r];
      }
    }
    Wzru[idx] = __float2half_rn(wv);
  } else if (idx < n_ru + n_c) {
    int i = idx - n_ru;
    int j = i & 7, ln = (i >> 3) & 63, rest = i >> 9;
    int k = (rest % 12)*32 + (ln >> 4)*8 + j;
    int o = (rest / 12)*16 + (ln & 15);
    float wv = 0.f;
    if (k < 360) {
      int p = k/72, d = k - p*72;
      if (d < 66) {
        int r = (d*MMATS + p)*64 + o;
        wv = mu_w_c[r] + expf(ls_w_c[r]) * eps_w_c[r];
      }
    }
    Wzc[i] = __float2half_rn(wv);
  } else if (idx < n_ru + n_c + 128) {
    int i = idx - n_ru - n_c;
    bru[i] = mu_b_ru[i] + expf(ls_b_ru[i]) * eps_b_ru[i];
  } else if (idx < n_ru + n_c + 128 + 64) {
    int i = idx - n_ru - n_c - 128;
    bc[i] = mu_b_c[i] + expf(ls_b_c[i]) * eps_b_c[i];
  }
}

// ---------------- ELL build (order within row irrelevant for a sum) --
__global__ __launch_bounds__(256) void k_ell(
    const float* __restrict__ supp, unsigned short* __restrict__ cols,
    float* __restrict__ vals, int* __restrict__ cnt)
{
  int j = blockIdx.x*256 + threadIdx.x;
  if (j >= N_NODES) return;
  int n = blockIdx.y, s = blockIdx.z;
  int r = s*N_NODES + n;
  float v = supp[(size_t)r*N_NODES + j];
  if (v != 0.f) {
    int p = atomicAdd(cnt + r, 1);
    if (p < ELLW) {
      cols[(size_t)r*ELLW + p] = (unsigned short)j;
      vals[(size_t)r*ELLW + p] = v;
    }
  }
}

// ---------------- build x0 plane (p=0) + zero pad blocks -------------
// XA micro-block layout per (cc,n): [48kb][8bs][8k] halfs (1536 dwords).
__global__ __launch_bounds__(256) void k_build0(
    const float* __restrict__ inp, const float* __restrict__ hx,
    const h16* __restrict__ VALr, unsigned int* __restrict__ XAu, int mode)
{
  const int n = blockIdx.x;
  const int g = threadIdx.x >> 5, tt = threadIdx.x & 31;
  const int b = g*8 + (tt >> 2);
  unsigned int* dst = XAu + (size_t)g*SLICE_DW + (size_t)n*NSTRIDE;
  #pragma unroll
  for (int kb = 0; kb < 9; ++kb) {
    int d0 = kb*8 + 2*(tt & 3);
    float v[2];
    #pragma unroll
    for (int q = 0; q < 2; ++q) {
      int d = d0 + q;
      float x = 0.f;
      if (d < 2) {
        x = inp[(size_t)b*(N_NODES*2) + n*2 + d];
      } else if (d < 66) {
        x = hx[(size_t)b*(N_NODES*64) + n*64 + (d-2)];
        if (mode == 1) x *= __half2float(VALr[(size_t)n*8192 + b*128 + (d-2)]);
      }
      v[q] = x;
    }
    dst[kb*32 + tt] = packh(v[0], v[1]);
  }
  dst[45*32 + tt] = 0u;  // pad kbs 45..47 (k in [360,384))
  dst[46*32 + tt] = 0u;
  dst[47*32 + tt] = 0u;
}

// ---------------- SpMM: plane(1+2s) = S_s @ plane0 -------------------
// Regular stores: planes 1/3 must stay L2-hot for k_cheb's gathers.
__global__ __launch_bounds__(256) void k_spmm(
    unsigned int* __restrict__ XAu, const unsigned short* __restrict__ cols,
    const float* __restrict__ vals, const int* __restrict__ cnt)
{
  const int cc = blockIdx.x;
  const int r  = blockIdx.y*8 + (threadIdx.x >> 5);
  const int tt = threadIdx.x & 31;
  const int s  = (r >= N_NODES) ? 1 : 0;
  const int n  = r - s*N_NODES;
  int c = cnt[r]; if (c > ELLW) c = ELLW;
  const unsigned short* cp = cols + (size_t)r*ELLW;
  const float*          vp = vals + (size_t)r*ELLW;
  const unsigned int* slice = XAu + (size_t)cc*SLICE_DW;   // plane 0 offset 0
  float2 acc[9];
  #pragma unroll
  for (int i = 0; i < 9; ++i) acc[i] = make_float2(0.f, 0.f);
  for (int k = 0; k < c; ++k) {
    int j = cp[k]; float v = vp[k];
    const unsigned int* s0 = slice + (size_t)j*NSTRIDE + tt;
    #pragma unroll
    for (int i = 0; i < 9; ++i) {
      float2 f = u2f2(s0[i*32]);
      acc[i].x = fmaf(v, f.x, acc[i].x);
      acc[i].y = fmaf(v, f.y, acc[i].y);
    }
  }
  unsigned int* dp = XAu + (size_t)cc*SLICE_DW + (size_t)n*NSTRIDE
                   + PLANE_OFF(1 + 2*s) + tt;
  #pragma unroll
  for (int i = 0; i < 9; ++i)
    dp[i*32] = packh(acc[i].x, acc[i].y);
}

// ---------------- Chebyshev: plane(2+2s) = 2*S_s@plane(1+2s) - plane0 -
__global__ __launch_bounds__(256) void k_cheb(
    unsigned int* __restrict__ XAu, const unsigned short* __restrict__ cols,
    const float* __restrict__ vals, const int* __restrict__ cnt)
{
  const int cc = blockIdx.x;
  const int r  = blockIdx.y*8 + (threadIdx.x >> 5);
  const int tt = threadIdx.x & 31;
  const int s  = (r >= N_NODES) ? 1 : 0;
  const int n  = r - s*N_NODES;
  int c = cnt[r]; if (c > ELLW) c = ELLW;
  const unsigned short* cp = cols + (size_t)r*ELLW;
  const float*          vp = vals + (size_t)r*ELLW;
  const unsigned int* slice = XAu + (size_t)cc*SLICE_DW + PLANE_OFF(1 + 2*s);
  float2 acc[9];
  #pragma unroll
  for (int i = 0; i < 9; ++i) acc[i] = make_float2(0.f, 0.f);
  for (int k = 0; k < c; ++k) {
    int j = cp[k]; float v = vp[k];
    const unsigned int* s0 = slice + (size_t)j*NSTRIDE + tt;
    #pragma unroll
    for (int i = 0; i < 9; ++i) {
      float2 f = u2f2(s0[i*32]);
      acc[i].x = fmaf(v, f.x, acc[i].x);
      acc[i].y = fmaf(v, f.y, acc[i].y);
    }
  }
  const unsigned int* xp = XAu + (size_t)cc*SLICE_DW + (size_t)n*NSTRIDE + tt; // plane 0
  unsigned int* dp = XAu + (size_t)cc*SLICE_DW + (size_t)n*NSTRIDE
                   + PLANE_OFF(2 + 2*s) + tt;
  #pragma unroll
  for (int i = 0; i < 9; ++i) {
    float2 f0 = u2f2(__builtin_nontemporal_load(xp + i*32));
    __builtin_nontemporal_store(packh(2.f*acc[i].x - f0.x, 2.f*acc[i].y - f0.y),
                                dp + i*32);
  }
}

// ---------------- projection via MFMA 16x16x32 f16, LDS-free ---------
// mode 0: VAL[n][b][o] = sigmoid(acc+bias) fp16  (nt=8)
// mode 1: out = u*hx + (1-u)*tanh(acc+bias) fp32 (nt=4)
__global__ __launch_bounds__(256) void k_projm(
    const unsigned int* __restrict__ XAu, const h16* __restrict__ Wz,
    const float* __restrict__ bias, h16* __restrict__ VAL,
    const float* __restrict__ hx, const h16* __restrict__ VALu,
    float* __restrict__ out, int mode)
{
  const int n = blockIdx.x;
  const int t = threadIdx.x;
  const int w = t >> 6, lane = t & 63;
  const int quad = lane >> 4, lr = lane & 15;
  const int b0 = w*16;
  const int cc = 2*w + (lr >> 3), bs = lr & 7;
  const int nt = mode ? 4 : 8;

  f32x4 acc[8];
  #pragma unroll
  for (int i = 0; i < 8; ++i) acc[i] = (f32x4){0.f,0.f,0.f,0.f};

  const h16* abase = (const h16*)(XAu + (size_t)cc*SLICE_DW + (size_t)n*NSTRIDE)
                   + bs*8 + quad*64;
  const f16x8* wbase = (const f16x8*)Wz + lane;
  for (int k0 = 0; k0 < 12; ++k0) {
    f16x8 a = *(const f16x8*)(abase + k0*256);
    const f16x8* wk = wbase + (size_t)k0*64;
    for (int ot = 0; ot < nt; ++ot) {
      f16x8 bf = wk[(size_t)ot*768];           // ((ot*12+k0)*64 + lane)
      acc[ot] = __builtin_amdgcn_mfma_f32_16x16x32_f16(a, bf, acc[ot], 0, 0, 0);
    }
  }

  if (mode == 0) {
    for (int ot = 0; ot < 8; ++ot) {
      int o = ot*16 + lr;
      float bia = bias[o];
      #pragma unroll
      for (int r = 0; r < 4; ++r) {
        int b = b0 + quad*4 + r;
        VAL[(size_t)n*8192 + b*128 + o] = __float2half_rn(fsigmoid(acc[ot][r] + bia));
      }
    }
  } else {
    for (int ot = 0; ot < 4; ++ot) {
      int o = ot*16 + lr;
      float bia = bias[o];
      #pragma unroll
      for (int r = 0; r < 4; ++r) {
        int b = b0 + quad*4 + r;
        float cv = ftanh(acc[ot][r] + bia);
        float u  = __half2float(VALu[(size_t)n*8192 + b*128 + 64 + o]);
        float h  = hx[(size_t)b*(N_NODES*64) + n*64 + o];
        out[(size_t)b*(N_NODES*64) + n*64 + o] = u*h + (1.f - u)*cv;
      }
    }
  }
}

extern "C" void kernel_launch(void* const* d_in, const int* in_sizes, int n_in,
                              void* d_out, int out_size, void* d_ws, size_t ws_size,
                              hipStream_t stream)
{
  const float* inp      = (const float*)d_in[0];
  const float* hx       = (const float*)d_in[1];
  const float* supp     = (const float*)d_in[2];
  const float* mu_w_ru  = (const float*)d_in[3];
  const float* ls_w_ru  = (const float*)d_in[4];
  const float* mu_b_ru  = (const float*)d_in[5];
  const float* ls_b_ru  = (const float*)d_in[6];
  const float* eps_w_ru = (const float*)d_in[7];
  const float* eps_b_ru = (const float*)d_in[8];
  const float* mu_w_c   = (const float*)d_in[9];
  const float* ls_w_c   = (const float*)d_in[10];
  const float* mu_b_c   = (const float*)d_in[11];
  const float* ls_b_c   = (const float*)d_in[12];
  const float* eps_w_c  = (const float*)d_in[13];
  const float* eps_b_c  = (const float*)d_in[14];
  float* out = (float*)d_out;

  char* wsp = (char*)d_ws;
  size_t off = 0;
  auto take = [&](size_t bytes) -> void* {
    void* p = wsp + off;
    off = (off + bytes + 255) & ~(size_t)255;
    return p;
  };
  unsigned int* XAu = (unsigned int*)take(8*SLICE_DW*sizeof(unsigned int)); // 98.3 MB
  h16*   VAL = (h16*)  take((size_t)N_NODES*8192*sizeof(h16));       // 32.8 MB
  h16*   Wzru= (h16*)  take((size_t)8*12*64*8*sizeof(h16));          // 98.3 KB
  h16*   Wzc = (h16*)  take((size_t)4*12*64*8*sizeof(h16));          // 49.2 KB
  float* bru = (float*)take(128*sizeof(float));
  float* bc  = (float*)take(64*sizeof(float));
  unsigned short* ellc = (unsigned short*)take((size_t)2*N_NODES*ELLW*sizeof(unsigned short));
  float* ellv= (float*)take((size_t)2*N_NODES*ELLW*sizeof(float));
  int*   cnt = (int*)  take((size_t)2*N_NODES*sizeof(int));
  // total ~134.5 MB (fits: R9 ran at this footprint)
  (void)ws_size;

  hipMemsetAsync(cnt, 0, (size_t)2*N_NODES*sizeof(int), stream);
  k_weights<<<289, 256, 0, stream>>>(mu_w_ru, ls_w_ru, eps_w_ru,
                                     mu_b_ru, ls_b_ru, eps_b_ru,
                                     mu_w_c, ls_w_c, eps_w_c,
                                     mu_b_c, ls_b_c, eps_b_c,
                                     Wzru, bru, Wzc, bc);
  k_ell<<<dim3(8, N_NODES, 2), 256, 0, stream>>>(supp, ellc, ellv, cnt);

  for (int pass = 0; pass < 2; ++pass) {
    k_build0<<<N_NODES, 256, 0, stream>>>(inp, hx, VAL, XAu, pass);
    k_spmm <<<dim3(8, 500), 256, 0, stream>>>(XAu, ellc, ellv, cnt);
    k_cheb <<<dim3(8, 500), 256, 0, stream>>>(XAu, ellc, ellv, cnt);
    if (pass == 0)
      k_projm<<<N_NODES, 256, 0, stream>>>(XAu, Wzru, bru, VAL,
                                           nullptr, nullptr, nullptr, 0);
    else
      k_projm<<<N_NODES, 256, 0, stream>>>(XAu, Wzc, bc, nullptr,
                                           hx, VAL, out, 1);
  }
}